// Round 5
// baseline (18633.224 us; speedup 1.0000x reference)
//
#include <hip/hip_runtime.h>
#include <stdint.h>

#define BATCH 8
#define NPTS 4096
#define KNN 20
#define NSPLIT 8
#define CAND_PER_SPLIT (NPTS / NSPLIT)    // 512
#define TILE 64
#define NTILES (CAND_PER_SPLIT / TILE)    // 8
#define CAP 6                             // flush trigger
#define CAPMAX 10                         // FIFO capacity (CAP-1 + 4 slack <= 10)
#define KTHR 128                          // knn2 block size
constexpr float SLOPE = 0.2f;

typedef unsigned long long u64;
// hi word unpacks to FLT_MAX (finite, NOT NaN) -> threshold stays permissive
// until the list holds 20 real entries.
#define INIT_KEY 0xFF7FFFFFFFFFFFFFULL

// ---------------------------------------------------------------------------
// shared exact-math dot chains (used by BOTH knn2 and merge so re-ranked
// distances are bit-identical to the in-kernel ones)
// ---------------------------------------------------------------------------
__device__ __forceinline__ float dot64_chain(const float4* __restrict__ xq,
                                             const float* __restrict__ row) {
    float acc = 0.f;
    #pragma unroll
    for (int k = 0; k < 16; ++k) {
        const float4 b = *(const float4*)&row[4 * k];
        acc = fmaf(xq[k].x, b.x, acc);
        acc = fmaf(xq[k].y, b.y, acc);
        acc = fmaf(xq[k].z, b.z, acc);
        acc = fmaf(xq[k].w, b.w, acc);
    }
    return acc;
}
__device__ __forceinline__ float dot3_chain(const float4 xq,
                                            const float* __restrict__ row) {
    float acc = 0.f;
    acc = fmaf(xq.x, row[0], acc);
    acc = fmaf(xq.y, row[1], acc);
    acc = fmaf(xq.z, row[2], acc);
    return acc;
}

// ---------------------------------------------------------------------------
// squared norms
// ---------------------------------------------------------------------------
template<int D>
__global__ __launch_bounds__(256) void sq_kernel(const float* __restrict__ X,
                                                 float* __restrict__ sq) {
    const int i = blockIdx.x * 256 + threadIdx.x;
    if constexpr (D == 3) {
        const float* p = X + (size_t)i * 3;
        float s = 0.f;
        s += p[0] * p[0]; s += p[1] * p[1]; s += p[2] * p[2];
        sq[i] = s;
    } else {
        const float4* p = (const float4*)(X + (size_t)i * 64);
        float s = 0.f;
        #pragma unroll
        for (int k = 0; k < 16; ++k) {
            float4 v = p[k];
            s += v.x * v.x; s += v.y * v.y; s += v.z * v.z; s += v.w * v.w;
        }
        sq[i] = s;
    }
}

// ---------------------------------------------------------------------------
// key packing: monotone float bits << 32 | j  (min == nearest, ties -> low j)
// ---------------------------------------------------------------------------
__device__ __forceinline__ u64 pack_key(float d, unsigned j) {
    unsigned ub = __float_as_uint(d);
    ub = (ub & 0x80000000u) ? ~ub : (ub | 0x80000000u);
    return ((u64)ub << 32) | j;
}
__device__ __forceinline__ float key_hi_to_d(unsigned hi) {
    unsigned u = (hi & 0x80000000u) ? (hi ^ 0x80000000u) : ~hi;
    return __uint_as_float(u);
}
__device__ __forceinline__ void insert_key(u64 (&lst)[KNN], u64 c) {
    #pragma unroll
    for (int k = 0; k < KNN; ++k) {
        const u64 lo = (lst[k] < c) ? lst[k] : c;
        const u64 hi = (lst[k] < c) ? c : lst[k];
        lst[k] = lo; c = hi;
    }
}
__device__ __forceinline__ void flush_buf(u64 (&lst)[KNN], const u64* __restrict__ buf,
                                          int t, int& cnt, float& tmax) {
    for (int i = 0; i < CAPMAX; ++i) {
        if (i < cnt) {
            const u64 key = buf[i * KTHR + t];
            if (key < lst[KNN - 1]) insert_key(lst, key);
        }
    }
    cnt = 0;
    tmax = key_hi_to_d((unsigned)(lst[KNN - 1] >> 32));
}

// ---------------------------------------------------------------------------
// kNN: query-per-thread, LDS-broadcast candidates, reg-staged tile prefetch,
// threshold+FIFO selection with wave-uniform flush. Emits per-split top-20
// candidate INDICES only (u32); merge re-ranks with bit-identical math.
// grid: (NPTS/KTHR, NSPLIT, BATCH), KTHR threads, 3 waves/SIMD.
// ---------------------------------------------------------------------------
template<int D>   // 3 or 64
__global__ __launch_bounds__(KTHR, 3) void knn2_kernel(
    const float* __restrict__ X, const float* __restrict__ sq,
    unsigned* __restrict__ part)      // [NSPLIT][KNN][B*N]
{
    __shared__ alignas(16) float xt[TILE * ((D == 3) ? 3 : 64)];
    __shared__ float sqt[TILE];
    __shared__ u64 buf[CAPMAX * KTHR];     // lane-interleaved FIFO: buf[i][t]

    const int t = threadIdx.x;
    const int split = blockIdx.y, b = blockIdx.z;
    const int q = blockIdx.x * KTHR + t;   // local to batch
    const float* Xb = X + (size_t)b * NPTS * D;
    const float* sqb = sq + (size_t)b * NPTS;
    const size_t BN = (size_t)BATCH * NPTS;

    float4 xq[(D == 3) ? 1 : 16];
    if constexpr (D == 3) {
        const float* qp = Xb + (size_t)q * 3;
        xq[0].x = qp[0]; xq[0].y = qp[1]; xq[0].z = qp[2]; xq[0].w = 0.f;
    } else {
        #pragma unroll
        for (int k = 0; k < 16; ++k)
            xq[k] = *(const float4*)&Xb[(size_t)q * 64 + 4 * k];
    }
    const float sqq = sqb[q];

    u64 lst[KNN];
    #pragma unroll
    for (int k = 0; k < KNN; ++k) lst[k] = INIT_KEY;
    float tmax = 3.402823466e38f;
    int cnt = 0;

    // ---- prologue: stage tile 0 into registers
    float4 preg[(D == 3) ? 1 : 8];
    float sprg = 0.f;
    {
        const int cbase = split * CAND_PER_SPLIT;
        if constexpr (D == 3) {
            if (t < 48) preg[0] = *(const float4*)&Xb[(size_t)cbase * 3 + 4 * t];
        } else {
            #pragma unroll
            for (int i = 0; i < 8; ++i)
                preg[i] = *(const float4*)&Xb[(size_t)cbase * 64 + 4 * (i * KTHR + t)];
        }
        if (t < 64) sprg = sqb[cbase + t];
    }

    for (int tile = 0; tile < NTILES; ++tile) {
        __syncthreads();   // previous tile's consumers done
        // commit staged registers to LDS
        if constexpr (D == 3) {
            if (t < 48) *(float4*)&xt[4 * t] = preg[0];
        } else {
            #pragma unroll
            for (int i = 0; i < 8; ++i)
                *(float4*)&xt[4 * (i * KTHR + t)] = preg[i];
        }
        if (t < 64) sqt[t] = sprg;
        // issue next tile's global loads (latency hides under compute)
        if (tile + 1 < NTILES) {
            const int nbase = split * CAND_PER_SPLIT + (tile + 1) * TILE;
            if constexpr (D == 3) {
                if (t < 48) preg[0] = *(const float4*)&Xb[(size_t)nbase * 3 + 4 * t];
            } else {
                #pragma unroll
                for (int i = 0; i < 8; ++i)
                    preg[i] = *(const float4*)&Xb[(size_t)nbase * 64 + 4 * (i * KTHR + t)];
            }
            if (t < 64) sprg = sqb[nbase + t];
        }
        __syncthreads();   // xt ready

        const int cbase = split * CAND_PER_SPLIT + tile * TILE;
        for (int c0 = 0; c0 < TILE; c0 += 4) {
            float d0, d1, d2, d3;
            if constexpr (D == 3) {
                d0 = sqq + sqt[c0 + 0] - 2.f * dot3_chain(xq[0], &xt[(c0 + 0) * 3]);
                d1 = sqq + sqt[c0 + 1] - 2.f * dot3_chain(xq[0], &xt[(c0 + 1) * 3]);
                d2 = sqq + sqt[c0 + 2] - 2.f * dot3_chain(xq[0], &xt[(c0 + 2) * 3]);
                d3 = sqq + sqt[c0 + 3] - 2.f * dot3_chain(xq[0], &xt[(c0 + 3) * 3]);
            } else {
                float a0 = 0.f, a1 = 0.f, a2 = 0.f, a3 = 0.f;
                const float* r0 = &xt[(c0 + 0) * 64];
                const float* r1 = &xt[(c0 + 1) * 64];
                const float* r2 = &xt[(c0 + 2) * 64];
                const float* r3 = &xt[(c0 + 3) * 64];
                #pragma unroll
                for (int k = 0; k < 16; ++k) {
                    const float4 aq = xq[k];
                    const float4 b0 = *(const float4*)&r0[4 * k];
                    const float4 b1 = *(const float4*)&r1[4 * k];
                    const float4 b2 = *(const float4*)&r2[4 * k];
                    const float4 b3 = *(const float4*)&r3[4 * k];
                    a0 = fmaf(aq.x, b0.x, a0); a0 = fmaf(aq.y, b0.y, a0);
                    a0 = fmaf(aq.z, b0.z, a0); a0 = fmaf(aq.w, b0.w, a0);
                    a1 = fmaf(aq.x, b1.x, a1); a1 = fmaf(aq.y, b1.y, a1);
                    a1 = fmaf(aq.z, b1.z, a1); a1 = fmaf(aq.w, b1.w, a1);
                    a2 = fmaf(aq.x, b2.x, a2); a2 = fmaf(aq.y, b2.y, a2);
                    a2 = fmaf(aq.z, b2.z, a2); a2 = fmaf(aq.w, b2.w, a2);
                    a3 = fmaf(aq.x, b3.x, a3); a3 = fmaf(aq.y, b3.y, a3);
                    a3 = fmaf(aq.z, b3.z, a3); a3 = fmaf(aq.w, b3.w, a3);
                }
                d0 = sqq + sqt[c0 + 0] - 2.f * a0;
                d1 = sqq + sqt[c0 + 1] - 2.f * a1;
                d2 = sqq + sqt[c0 + 2] - 2.f * a2;
                d3 = sqq + sqt[c0 + 3] - 2.f * a3;
            }
            if ((d0 <= tmax) | (d1 <= tmax) | (d2 <= tmax) | (d3 <= tmax)) {
                if (d0 <= tmax) { buf[cnt * KTHR + t] = pack_key(d0, cbase + c0 + 0); ++cnt; }
                if (d1 <= tmax) { buf[cnt * KTHR + t] = pack_key(d1, cbase + c0 + 1); ++cnt; }
                if (d2 <= tmax) { buf[cnt * KTHR + t] = pack_key(d2, cbase + c0 + 2); ++cnt; }
                if (d3 <= tmax) { buf[cnt * KTHR + t] = pack_key(d3, cbase + c0 + 3); ++cnt; }
            }
            // wave-uniform flush; max +4 since last check so cnt <= 9 < CAPMAX
            if (__any(cnt >= CAP)) flush_buf(lst, buf, t, cnt, tmax);
        }
    }
    if (__any(cnt > 0)) flush_buf(lst, buf, t, cnt, tmax);

    // store per-split top-20 indices only (coalesced)
    #pragma unroll
    for (int k = 0; k < KNN; ++k)
        part[((size_t)split * KNN + k) * BN + (size_t)b * NPTS + q] =
            (unsigned)(lst[k] & 0xffffffffu);
}

// ---------------------------------------------------------------------------
// merge: re-rank the union of 8 per-split top-20s with BIT-IDENTICAL fp32
// math and output exact global top-20. 4 threads/query (2 splits each),
// 4-way sorted merge in LDS. grid: BN/64 blocks, 256 threads.
// ---------------------------------------------------------------------------
template<int D>
__global__ __launch_bounds__(256) void merge_kernel(
    const float* __restrict__ X, const float* __restrict__ sq,
    const unsigned* __restrict__ part, int* __restrict__ idx) {
    __shared__ u64 lls[256 * 21];    // stride 21: pad slot = sentinel

    const int t = threadIdx.x;
    const int sub = t & 3;
    const int q = blockIdx.x * 64 + (t >> 2);     // global over B*N
    const int b = q >> 12;
    const int qn = q & (NPTS - 1);
    const float* Xb = X + (size_t)b * NPTS * D;
    const float* sqb = sq + (size_t)b * NPTS;
    const size_t BN = (size_t)BATCH * NPTS;

    float4 xq[(D == 3) ? 1 : 16];
    if constexpr (D == 3) {
        const float* qp = Xb + (size_t)qn * 3;
        xq[0].x = qp[0]; xq[0].y = qp[1]; xq[0].z = qp[2]; xq[0].w = 0.f;
    } else {
        #pragma unroll
        for (int k = 0; k < 16; ++k)
            xq[k] = *(const float4*)&Xb[(size_t)qn * 64 + 4 * k];
    }
    const float sqq = sqb[qn];

    u64 lst[KNN];
    #pragma unroll
    for (int k = 0; k < KNN; ++k) lst[k] = INIT_KEY;

    for (int s = sub * 2; s < sub * 2 + 2; ++s) {
        for (int k = 0; k < KNN; ++k) {
            const unsigned j = part[((size_t)s * KNN + k) * BN + q];
            float dd;
            if constexpr (D == 3)
                dd = sqq + sqb[j] - 2.f * dot3_chain(xq[0], &Xb[(size_t)j * 3]);
            else
                dd = sqq + sqb[j] - 2.f * dot64_chain(xq, &Xb[(size_t)j * 64]);
            const u64 key = pack_key(dd, j);
            if (key < lst[KNN - 1]) insert_key(lst, key);
        }
    }

    #pragma unroll
    for (int k = 0; k < KNN; ++k) lls[t * 21 + k] = lst[k];
    lls[t * 21 + 20] = ~0ULL;       // sentinel for merge overrun
    __syncthreads();

    if (sub == 0) {
        const u64* L0 = &lls[(t + 0) * 21];
        const u64* L1 = &lls[(t + 1) * 21];
        const u64* L2 = &lls[(t + 2) * 21];
        const u64* L3 = &lls[(t + 3) * 21];
        int p0 = 0, p1 = 0, p2 = 0, p3 = 0;
        int* outp = idx + (size_t)q * KNN;
        for (int k = 0; k < KNN; ++k) {
            const u64 h0 = L0[p0], h1 = L1[p1], h2 = L2[p2], h3 = L3[p3];
            const u64 m01 = (h0 < h1) ? h0 : h1;
            const u64 m23 = (h2 < h3) ? h2 : h3;
            const u64 m = (m01 < m23) ? m01 : m23;
            outp[k] = (int)(unsigned)(m & 0xffffffffu);
            if (m == h0) ++p0; else if (m == h1) ++p1; else if (m == h2) ++p2; else ++p3;
        }
    }
}

// ---------------------------------------------------------------------------
// per-point u = X @ W1b, c = X @ W1a - u + b1
//   h1(i,j) = lrelu([x_i | x_j-x_i] @ W1 + b1) = lrelu(c_i + u_j)
// ---------------------------------------------------------------------------
template<int D>
__global__ __launch_bounds__(256) void uc_kernel(
    const float* __restrict__ X, const float* __restrict__ W1,
    const float* __restrict__ b1, float* __restrict__ u, float* __restrict__ cvec) {
    __shared__ float Xs[16 * D];
    const int n0 = blockIdx.x * 16;
    const int t = threadIdx.x;
    for (int i = t; i < 16 * D; i += 256)
        Xs[i] = X[(size_t)n0 * D + i];
    __syncthreads();

    const int o = t & 63;
    const int pg = t >> 6;
    float va[4] = {0.f, 0.f, 0.f, 0.f};
    float vb[4] = {0.f, 0.f, 0.f, 0.f};
    for (int d = 0; d < D; ++d) {
        const float wa = W1[d * 64 + o];
        const float wb = W1[(D + d) * 64 + o];
        #pragma unroll
        for (int pi = 0; pi < 4; ++pi) {
            const float x = Xs[(pg * 4 + pi) * D + d];
            va[pi] += x * wa;
            vb[pi] += x * wb;
        }
    }
    const float bo = b1[o];
    #pragma unroll
    for (int pi = 0; pi < 4; ++pi) {
        const size_t n = (size_t)n0 + pg * 4 + pi;
        u[n * 64 + o] = vb[pi];
        cvec[n * 64 + o] = va[pi] - vb[pi] + bo;
    }
}

// ---------------------------------------------------------------------------
// fused edge MLP + max aggregation (single h buffer; acc lives in regs
// across the barrier, h2 written back into h1s; W3 staged after GEMM1)
// ---------------------------------------------------------------------------
__device__ __forceinline__ void gemm_acc(const float* __restrict__ Xs,
                                         const float* __restrict__ Ws,
                                         const float* __restrict__ bias,
                                         float (&acc)[5][4], const int t) {
    const int rg = t >> 4, og = t & 15;
    #pragma unroll
    for (int oc = 0; oc < 4; ++oc) {
        const float bb = bias[4 * og + oc];
        #pragma unroll
        for (int rr = 0; rr < 5; ++rr) acc[rr][oc] = bb;
    }
    #pragma unroll
    for (int k4 = 0; k4 < 16; ++k4) {
        float4 xv[5];
        #pragma unroll
        for (int rr = 0; rr < 5; ++rr)
            xv[rr] = *(const float4*)&Xs[(5 * rg + rr) * 68 + 4 * k4];
        float4 wv[4];
        #pragma unroll
        for (int kk = 0; kk < 4; ++kk)
            wv[kk] = *(const float4*)&Ws[(4 * k4 + kk) * 64 + 4 * og];
        #pragma unroll
        for (int rr = 0; rr < 5; ++rr) {
            acc[rr][0] += xv[rr].x * wv[0].x + xv[rr].y * wv[1].x + xv[rr].z * wv[2].x + xv[rr].w * wv[3].x;
            acc[rr][1] += xv[rr].x * wv[0].y + xv[rr].y * wv[1].y + xv[rr].z * wv[2].y + xv[rr].w * wv[3].y;
            acc[rr][2] += xv[rr].x * wv[0].z + xv[rr].y * wv[1].z + xv[rr].z * wv[2].z + xv[rr].w * wv[3].z;
            acc[rr][3] += xv[rr].x * wv[0].w + xv[rr].y * wv[1].w + xv[rr].z * wv[2].w + xv[rr].w * wv[3].w;
        }
    }
}

__global__ __launch_bounds__(256) void edge_kernel(
    const float* __restrict__ u, const float* __restrict__ cvec,
    const int* __restrict__ knn_idx,
    const float* __restrict__ W2, const float* __restrict__ b2,
    const float* __restrict__ W3, const float* __restrict__ b3,
    float* __restrict__ out) {
    __shared__ alignas(16) float h1s[80 * 68];
    __shared__ alignas(16) float Ws[64 * 64];
    __shared__ float cs[256];
    __shared__ float mxs[16 * 64];
    __shared__ int idxs[80];

    const int t = threadIdx.x;
    const int p0 = blockIdx.x * 4;
    const int b = p0 >> 12;

    cs[t] = cvec[(size_t)p0 * 64 + t];
    if (t < 80) idxs[t] = knn_idx[(size_t)p0 * KNN + t];
    for (int i = t; i < 4096; i += 256) Ws[i] = W2[i];
    __syncthreads();

    {   // h1 = lrelu(c_i + u_j)
        const int wave = t >> 6, lane = t & 63;
        for (int e = wave; e < 80; e += 4) {
            const int j = idxs[e];
            const float val = u[((size_t)(b << 12) + j) * 64 + lane];
            const float pre = cs[(e / 20) * 64 + lane] + val;
            h1s[e * 68 + lane] = (pre > 0.f) ? pre : SLOPE * pre;
        }
    }
    __syncthreads();

    float acc[5][4];
    gemm_acc(h1s, Ws, b2, acc, t);      // GEMM1
    __syncthreads();

    {   // write h2 back into h1s; stage W3
        const int rg = t >> 4, og = t & 15;
        #pragma unroll
        for (int rr = 0; rr < 5; ++rr)
            #pragma unroll
            for (int oc = 0; oc < 4; ++oc) {
                float v = acc[rr][oc];
                v = (v > 0.f) ? v : SLOPE * v;
                h1s[(5 * rg + rr) * 68 + 4 * og + oc] = v;
            }
        for (int i = t; i < 4096; i += 256) Ws[i] = W3[i];
    }
    __syncthreads();

    gemm_acc(h1s, Ws, b3, acc, t);      // GEMM2
    {   // max over each thread's 5 rows (within one point: 20 % 5 == 0)
        const int rg = t >> 4, og = t & 15;
        #pragma unroll
        for (int oc = 0; oc < 4; ++oc) {
            float m = -1e30f;
            #pragma unroll
            for (int rr = 0; rr < 5; ++rr) {
                float v = acc[rr][oc];
                v = (v > 0.f) ? v : SLOPE * v;
                m = fmaxf(m, v);
            }
            mxs[rg * 64 + 4 * og + oc] = m;
        }
    }
    __syncthreads();

    const int p = t >> 6, col = t & 63;
    const float m = fmaxf(fmaxf(mxs[(4 * p + 0) * 64 + col], mxs[(4 * p + 1) * 64 + col]),
                          fmaxf(mxs[(4 * p + 2) * 64 + col], mxs[(4 * p + 3) * 64 + col]));
    out[(size_t)(p0 + p) * 64 + col] = m;
}

// ---------------------------------------------------------------------------
extern "C" void kernel_launch(void* const* d_in, const int* in_sizes, int n_in,
                              void* d_out, int out_size, void* d_ws, size_t ws_size,
                              hipStream_t stream) {
    const float* pos = (const float*)d_in[0];
    const float* w11 = (const float*)d_in[1];  const float* b11 = (const float*)d_in[2];
    const float* w12 = (const float*)d_in[3];  const float* b12 = (const float*)d_in[4];
    const float* w13 = (const float*)d_in[5];  const float* b13 = (const float*)d_in[6];
    const float* w21 = (const float*)d_in[7];  const float* b21 = (const float*)d_in[8];
    const float* w22 = (const float*)d_in[9];  const float* b22 = (const float*)d_in[10];
    const float* w23 = (const float*)d_in[11]; const float* b23 = (const float*)d_in[12];
    const float* w31 = (const float*)d_in[13]; const float* b31 = (const float*)d_in[14];
    const float* w32 = (const float*)d_in[15]; const float* b32 = (const float*)d_in[16];
    const float* w33 = (const float*)d_in[17]; const float* b33 = (const float*)d_in[18];

    const int BN = BATCH * NPTS;   // 32768
    // Workspace layout: [sqb][idx][x1][u][c][x2], 34.6 MB (same as R4).
    // part = NSPLIT*KNN*BN u32 = 21.0 MB, aliased per-conv onto DEAD buffers:
    //   conv1/conv3: part at x1 (spans x1,u,c = 24 MB; knn input pos/x2 disjoint)
    //   conv2:       part at u  (spans u,c,x2 = 24 MB; x1 is the live input)
    // Per conv: knn2 writes part -> merge re-ranks part into idx ->
    // uc overwrites u,c -> edge writes x1/x2/out.
    float* ws = (float*)d_ws;
    float* sqb = ws;                                  // [BN]
    int*   idx = (int*)(sqb + BN);                    // [BN][20]
    float* x1  = (float*)(idx + (size_t)BN * KNN);    // [BN][64]
    float* ubuf = x1 + (size_t)BN * 64;               // [BN][64]
    float* cbuf = ubuf + (size_t)BN * 64;             // [BN][64]
    float* x2  = cbuf + (size_t)BN * 64;              // [BN][64]
    unsigned* part13 = (unsigned*)x1;                 // conv1/conv3 partials
    unsigned* part2  = (unsigned*)ubuf;               // conv2 partials

    const dim3 knn_grid(NPTS / KTHR, NSPLIT, BATCH);

    // ---- EdgeConv 1 (D=3)
    sq_kernel<3><<<BN / 256, 256, 0, stream>>>(pos, sqb);
    knn2_kernel<3><<<knn_grid, KTHR, 0, stream>>>(pos, sqb, part13);
    merge_kernel<3><<<BN / 64, 256, 0, stream>>>(pos, sqb, part13, idx);
    uc_kernel<3><<<BN / 16, 256, 0, stream>>>(pos, w11, b11, ubuf, cbuf);
    edge_kernel<<<BN / 4, 256, 0, stream>>>(ubuf, cbuf, idx, w12, b12, w13, b13, x1);

    // ---- EdgeConv 2 (D=64)
    sq_kernel<64><<<BN / 256, 256, 0, stream>>>(x1, sqb);
    knn2_kernel<64><<<knn_grid, KTHR, 0, stream>>>(x1, sqb, part2);
    merge_kernel<64><<<BN / 64, 256, 0, stream>>>(x1, sqb, part2, idx);
    uc_kernel<64><<<BN / 16, 256, 0, stream>>>(x1, w21, b21, ubuf, cbuf);
    edge_kernel<<<BN / 4, 256, 0, stream>>>(ubuf, cbuf, idx, w22, b22, w23, b23, x2);

    // ---- EdgeConv 3 (D=64)
    sq_kernel<64><<<BN / 256, 256, 0, stream>>>(x2, sqb);
    knn2_kernel<64><<<knn_grid, KTHR, 0, stream>>>(x2, sqb, part13);
    merge_kernel<64><<<BN / 64, 256, 0, stream>>>(x2, sqb, part13, idx);
    uc_kernel<64><<<BN / 16, 256, 0, stream>>>(x2, w31, b31, ubuf, cbuf);
    edge_kernel<<<BN / 4, 256, 0, stream>>>(ubuf, cbuf, idx, w32, b32, w33, b33, (float*)d_out);
}

// Round 6
// 5298.988 us; speedup vs baseline: 3.5164x; 3.5164x over previous
//
#include <hip/hip_runtime.h>
#include <stdint.h>

#define BATCH 8
#define NPTS 4096
#define KNN 20
#define NSPLIT 8
#define CAND_PER_SPLIT (NPTS / NSPLIT)    // 512
#define TILE 64
#define NTILES (CAND_PER_SPLIT / TILE)    // 8
#define CAP 6                             // flush trigger
#define CAPMAX 10                         // FIFO capacity (CAP-1 + 4 slack <= 10)
#define KTHR 64                           // knn2 block size: 1 wave
constexpr float SLOPE = 0.2f;

typedef unsigned long long u64;
// hi word unpacks to FLT_MAX (finite, NOT NaN) -> threshold stays permissive
// until the list holds 20 real entries.
#define INIT_KEY 0xFF7FFFFFFFFFFFFFULL

// ---------------------------------------------------------------------------
// shared exact-math dot chains (used by BOTH knn2 and merge so re-ranked
// distances are bit-identical to the in-kernel ones)
// ---------------------------------------------------------------------------
__device__ __forceinline__ float dot64_chain(const float4* __restrict__ xq,
                                             const float* __restrict__ row) {
    float acc = 0.f;
    #pragma unroll
    for (int k = 0; k < 16; ++k) {
        const float4 b = *(const float4*)&row[4 * k];
        acc = fmaf(xq[k].x, b.x, acc);
        acc = fmaf(xq[k].y, b.y, acc);
        acc = fmaf(xq[k].z, b.z, acc);
        acc = fmaf(xq[k].w, b.w, acc);
    }
    return acc;
}
__device__ __forceinline__ float dot3_chain(const float4 xq,
                                            const float* __restrict__ row) {
    float acc = 0.f;
    acc = fmaf(xq.x, row[0], acc);
    acc = fmaf(xq.y, row[1], acc);
    acc = fmaf(xq.z, row[2], acc);
    return acc;
}

// ---------------------------------------------------------------------------
// squared norms
// ---------------------------------------------------------------------------
template<int D>
__global__ __launch_bounds__(256) void sq_kernel(const float* __restrict__ X,
                                                 float* __restrict__ sq) {
    const int i = blockIdx.x * 256 + threadIdx.x;
    if constexpr (D == 3) {
        const float* p = X + (size_t)i * 3;
        float s = 0.f;
        s += p[0] * p[0]; s += p[1] * p[1]; s += p[2] * p[2];
        sq[i] = s;
    } else {
        const float4* p = (const float4*)(X + (size_t)i * 64);
        float s = 0.f;
        #pragma unroll
        for (int k = 0; k < 16; ++k) {
            float4 v = p[k];
            s += v.x * v.x; s += v.y * v.y; s += v.z * v.z; s += v.w * v.w;
        }
        sq[i] = s;
    }
}

// ---------------------------------------------------------------------------
// key packing: monotone float bits << 32 | j  (min == nearest, ties -> low j)
// ---------------------------------------------------------------------------
__device__ __forceinline__ u64 pack_key(float d, unsigned j) {
    unsigned ub = __float_as_uint(d);
    ub = (ub & 0x80000000u) ? ~ub : (ub | 0x80000000u);
    return ((u64)ub << 32) | j;
}
__device__ __forceinline__ float key_hi_to_d(unsigned hi) {
    unsigned u = (hi & 0x80000000u) ? (hi ^ 0x80000000u) : ~hi;
    return __uint_as_float(u);
}
__device__ __forceinline__ void insert_key(u64 (&lst)[KNN], u64 c) {
    #pragma unroll
    for (int k = 0; k < KNN; ++k) {
        const u64 lo = (lst[k] < c) ? lst[k] : c;
        const u64 hi = (lst[k] < c) ? c : lst[k];
        lst[k] = lo; c = hi;
    }
}
__device__ __forceinline__ void flush_buf(u64 (&lst)[KNN], const u64* __restrict__ buf,
                                          int t, int& cnt, float& tmax) {
    for (int i = 0; i < CAPMAX; ++i) {
        if (i < cnt) {
            const u64 key = buf[i * KTHR + t];
            if (key < lst[KNN - 1]) insert_key(lst, key);
        }
    }
    cnt = 0;
    tmax = key_hi_to_d((unsigned)(lst[KNN - 1] >> 32));
}

// ---------------------------------------------------------------------------
// kNN: query-per-thread, LDS-broadcast candidates, threshold+FIFO selection
// with wave-uniform flush. Emits per-split top-20 candidate INDICES (u32);
// merge re-ranks with bit-identical math.
// grid: (NPTS/KTHR, NSPLIT, BATCH), 1-wave blocks (small LDS, many blocks/CU).
// NOTE: no min-waves launch bound and no register prefetch -- R5 proved the
// combination spills (VGPR 84 < demand ~170 -> 18 GB scratch traffic).
// ---------------------------------------------------------------------------
template<int D>   // 3 or 64
__global__ __launch_bounds__(KTHR) void knn2_kernel(
    const float* __restrict__ X, const float* __restrict__ sq,
    unsigned* __restrict__ part)      // [NSPLIT][KNN][B*N]
{
    __shared__ alignas(16) float xt[TILE * ((D == 3) ? 3 : 64)];
    __shared__ float sqt[TILE];
    __shared__ u64 buf[CAPMAX * KTHR];     // lane-interleaved FIFO: buf[i][t]

    const int t = threadIdx.x;
    const int split = blockIdx.y, b = blockIdx.z;
    const int q = blockIdx.x * KTHR + t;   // local to batch
    const float* Xb = X + (size_t)b * NPTS * D;
    const float* sqb = sq + (size_t)b * NPTS;
    const size_t BN = (size_t)BATCH * NPTS;

    float4 xq[(D == 3) ? 1 : 16];
    if constexpr (D == 3) {
        const float* qp = Xb + (size_t)q * 3;
        xq[0].x = qp[0]; xq[0].y = qp[1]; xq[0].z = qp[2]; xq[0].w = 0.f;
    } else {
        #pragma unroll
        for (int k = 0; k < 16; ++k)
            xq[k] = *(const float4*)&Xb[(size_t)q * 64 + 4 * k];
    }
    const float sqq = sqb[q];

    u64 lst[KNN];
    #pragma unroll
    for (int k = 0; k < KNN; ++k) lst[k] = INIT_KEY;
    float tmax = 3.402823466e38f;
    int cnt = 0;

    for (int tile = 0; tile < NTILES; ++tile) {
        const int cbase = split * CAND_PER_SPLIT + tile * TILE;
        __syncthreads();   // previous tile's consumers done (1 wave: cheap)
        // ---- stage candidate tile into LDS
        if constexpr (D == 3) {
            if (t < 48)
                *(float4*)&xt[4 * t] = *(const float4*)&Xb[(size_t)cbase * 3 + 4 * t];
        } else {
            #pragma unroll
            for (int i = 0; i < 16; ++i)
                *(float4*)&xt[4 * (i * KTHR + t)] =
                    *(const float4*)&Xb[(size_t)cbase * 64 + 4 * (i * KTHR + t)];
        }
        sqt[t] = sqb[cbase + t];
        __syncthreads();   // xt ready

        // ---- score 64 candidates (4 at a time, broadcast LDS reads)
        for (int c0 = 0; c0 < TILE; c0 += 4) {
            float d0, d1, d2, d3;
            if constexpr (D == 3) {
                d0 = sqq + sqt[c0 + 0] - 2.f * dot3_chain(xq[0], &xt[(c0 + 0) * 3]);
                d1 = sqq + sqt[c0 + 1] - 2.f * dot3_chain(xq[0], &xt[(c0 + 1) * 3]);
                d2 = sqq + sqt[c0 + 2] - 2.f * dot3_chain(xq[0], &xt[(c0 + 2) * 3]);
                d3 = sqq + sqt[c0 + 3] - 2.f * dot3_chain(xq[0], &xt[(c0 + 3) * 3]);
            } else {
                float a0 = 0.f, a1 = 0.f, a2 = 0.f, a3 = 0.f;
                const float* r0 = &xt[(c0 + 0) * 64];
                const float* r1 = &xt[(c0 + 1) * 64];
                const float* r2 = &xt[(c0 + 2) * 64];
                const float* r3 = &xt[(c0 + 3) * 64];
                #pragma unroll
                for (int k = 0; k < 16; ++k) {
                    const float4 aq = xq[k];
                    const float4 b0 = *(const float4*)&r0[4 * k];
                    const float4 b1 = *(const float4*)&r1[4 * k];
                    const float4 b2 = *(const float4*)&r2[4 * k];
                    const float4 b3 = *(const float4*)&r3[4 * k];
                    a0 = fmaf(aq.x, b0.x, a0); a0 = fmaf(aq.y, b0.y, a0);
                    a0 = fmaf(aq.z, b0.z, a0); a0 = fmaf(aq.w, b0.w, a0);
                    a1 = fmaf(aq.x, b1.x, a1); a1 = fmaf(aq.y, b1.y, a1);
                    a1 = fmaf(aq.z, b1.z, a1); a1 = fmaf(aq.w, b1.w, a1);
                    a2 = fmaf(aq.x, b2.x, a2); a2 = fmaf(aq.y, b2.y, a2);
                    a2 = fmaf(aq.z, b2.z, a2); a2 = fmaf(aq.w, b2.w, a2);
                    a3 = fmaf(aq.x, b3.x, a3); a3 = fmaf(aq.y, b3.y, a3);
                    a3 = fmaf(aq.z, b3.z, a3); a3 = fmaf(aq.w, b3.w, a3);
                }
                d0 = sqq + sqt[c0 + 0] - 2.f * a0;
                d1 = sqq + sqt[c0 + 1] - 2.f * a1;
                d2 = sqq + sqt[c0 + 2] - 2.f * a2;
                d3 = sqq + sqt[c0 + 3] - 2.f * a3;
            }
            if ((d0 <= tmax) | (d1 <= tmax) | (d2 <= tmax) | (d3 <= tmax)) {
                if (d0 <= tmax) { buf[cnt * KTHR + t] = pack_key(d0, cbase + c0 + 0); ++cnt; }
                if (d1 <= tmax) { buf[cnt * KTHR + t] = pack_key(d1, cbase + c0 + 1); ++cnt; }
                if (d2 <= tmax) { buf[cnt * KTHR + t] = pack_key(d2, cbase + c0 + 2); ++cnt; }
                if (d3 <= tmax) { buf[cnt * KTHR + t] = pack_key(d3, cbase + c0 + 3); ++cnt; }
            }
            // wave-uniform flush; max +4 since last check so cnt <= 9 < CAPMAX
            if (__any(cnt >= CAP)) flush_buf(lst, buf, t, cnt, tmax);
        }
    }
    if (__any(cnt > 0)) flush_buf(lst, buf, t, cnt, tmax);

    // store per-split top-20 indices only (coalesced)
    #pragma unroll
    for (int k = 0; k < KNN; ++k)
        part[((size_t)split * KNN + k) * BN + (size_t)b * NPTS + q] =
            (unsigned)(lst[k] & 0xffffffffu);
}

// ---------------------------------------------------------------------------
// merge: re-rank the union of 8 per-split top-20s with BIT-IDENTICAL fp32
// math and output exact global top-20. 4 threads/query (2 splits each),
// 4-way sorted merge in LDS. grid: BN/64 blocks, 256 threads.
// ---------------------------------------------------------------------------
template<int D>
__global__ __launch_bounds__(256) void merge_kernel(
    const float* __restrict__ X, const float* __restrict__ sq,
    const unsigned* __restrict__ part, int* __restrict__ idx) {
    __shared__ u64 lls[256 * 21];    // stride 21: pad slot = sentinel

    const int t = threadIdx.x;
    const int sub = t & 3;
    const int q = blockIdx.x * 64 + (t >> 2);     // global over B*N
    const int b = q >> 12;
    const int qn = q & (NPTS - 1);
    const float* Xb = X + (size_t)b * NPTS * D;
    const float* sqb = sq + (size_t)b * NPTS;
    const size_t BN = (size_t)BATCH * NPTS;

    float4 xq[(D == 3) ? 1 : 16];
    if constexpr (D == 3) {
        const float* qp = Xb + (size_t)qn * 3;
        xq[0].x = qp[0]; xq[0].y = qp[1]; xq[0].z = qp[2]; xq[0].w = 0.f;
    } else {
        #pragma unroll
        for (int k = 0; k < 16; ++k)
            xq[k] = *(const float4*)&Xb[(size_t)qn * 64 + 4 * k];
    }
    const float sqq = sqb[qn];

    u64 lst[KNN];
    #pragma unroll
    for (int k = 0; k < KNN; ++k) lst[k] = INIT_KEY;

    for (int s = sub * 2; s < sub * 2 + 2; ++s) {
        for (int k = 0; k < KNN; ++k) {
            const unsigned j = part[((size_t)s * KNN + k) * BN + q];
            float dd;
            if constexpr (D == 3)
                dd = sqq + sqb[j] - 2.f * dot3_chain(xq[0], &Xb[(size_t)j * 3]);
            else
                dd = sqq + sqb[j] - 2.f * dot64_chain(xq, &Xb[(size_t)j * 64]);
            const u64 key = pack_key(dd, j);
            if (key < lst[KNN - 1]) insert_key(lst, key);
        }
    }

    #pragma unroll
    for (int k = 0; k < KNN; ++k) lls[t * 21 + k] = lst[k];
    lls[t * 21 + 20] = ~0ULL;       // sentinel for merge overrun
    __syncthreads();

    if (sub == 0) {
        const u64* L0 = &lls[(t + 0) * 21];
        const u64* L1 = &lls[(t + 1) * 21];
        const u64* L2 = &lls[(t + 2) * 21];
        const u64* L3 = &lls[(t + 3) * 21];
        int p0 = 0, p1 = 0, p2 = 0, p3 = 0;
        int* outp = idx + (size_t)q * KNN;
        for (int k = 0; k < KNN; ++k) {
            const u64 h0 = L0[p0], h1 = L1[p1], h2 = L2[p2], h3 = L3[p3];
            const u64 m01 = (h0 < h1) ? h0 : h1;
            const u64 m23 = (h2 < h3) ? h2 : h3;
            const u64 m = (m01 < m23) ? m01 : m23;
            outp[k] = (int)(unsigned)(m & 0xffffffffu);
            if (m == h0) ++p0; else if (m == h1) ++p1; else if (m == h2) ++p2; else ++p3;
        }
    }
}

// ---------------------------------------------------------------------------
// per-point u = X @ W1b, c = X @ W1a - u + b1
//   h1(i,j) = lrelu([x_i | x_j-x_i] @ W1 + b1) = lrelu(c_i + u_j)
// ---------------------------------------------------------------------------
template<int D>
__global__ __launch_bounds__(256) void uc_kernel(
    const float* __restrict__ X, const float* __restrict__ W1,
    const float* __restrict__ b1, float* __restrict__ u, float* __restrict__ cvec) {
    __shared__ float Xs[16 * D];
    const int n0 = blockIdx.x * 16;
    const int t = threadIdx.x;
    for (int i = t; i < 16 * D; i += 256)
        Xs[i] = X[(size_t)n0 * D + i];
    __syncthreads();

    const int o = t & 63;
    const int pg = t >> 6;
    float va[4] = {0.f, 0.f, 0.f, 0.f};
    float vb[4] = {0.f, 0.f, 0.f, 0.f};
    for (int d = 0; d < D; ++d) {
        const float wa = W1[d * 64 + o];
        const float wb = W1[(D + d) * 64 + o];
        #pragma unroll
        for (int pi = 0; pi < 4; ++pi) {
            const float x = Xs[(pg * 4 + pi) * D + d];
            va[pi] += x * wa;
            vb[pi] += x * wb;
        }
    }
    const float bo = b1[o];
    #pragma unroll
    for (int pi = 0; pi < 4; ++pi) {
        const size_t n = (size_t)n0 + pg * 4 + pi;
        u[n * 64 + o] = vb[pi];
        cvec[n * 64 + o] = va[pi] - vb[pi] + bo;
    }
}

// ---------------------------------------------------------------------------
// fused edge MLP + max aggregation (single h buffer; acc lives in regs
// across the barrier, h2 written back into h1s; W3 staged after GEMM1)
// ---------------------------------------------------------------------------
__device__ __forceinline__ void gemm_acc(const float* __restrict__ Xs,
                                         const float* __restrict__ Ws,
                                         const float* __restrict__ bias,
                                         float (&acc)[5][4], const int t) {
    const int rg = t >> 4, og = t & 15;
    #pragma unroll
    for (int oc = 0; oc < 4; ++oc) {
        const float bb = bias[4 * og + oc];
        #pragma unroll
        for (int rr = 0; rr < 5; ++rr) acc[rr][oc] = bb;
    }
    #pragma unroll
    for (int k4 = 0; k4 < 16; ++k4) {
        float4 xv[5];
        #pragma unroll
        for (int rr = 0; rr < 5; ++rr)
            xv[rr] = *(const float4*)&Xs[(5 * rg + rr) * 68 + 4 * k4];
        float4 wv[4];
        #pragma unroll
        for (int kk = 0; kk < 4; ++kk)
            wv[kk] = *(const float4*)&Ws[(4 * k4 + kk) * 64 + 4 * og];
        #pragma unroll
        for (int rr = 0; rr < 5; ++rr) {
            acc[rr][0] += xv[rr].x * wv[0].x + xv[rr].y * wv[1].x + xv[rr].z * wv[2].x + xv[rr].w * wv[3].x;
            acc[rr][1] += xv[rr].x * wv[0].y + xv[rr].y * wv[1].y + xv[rr].z * wv[2].y + xv[rr].w * wv[3].y;
            acc[rr][2] += xv[rr].x * wv[0].z + xv[rr].y * wv[1].z + xv[rr].z * wv[2].z + xv[rr].w * wv[3].z;
            acc[rr][3] += xv[rr].x * wv[0].w + xv[rr].y * wv[1].w + xv[rr].z * wv[2].w + xv[rr].w * wv[3].w;
        }
    }
}

__global__ __launch_bounds__(256) void edge_kernel(
    const float* __restrict__ u, const float* __restrict__ cvec,
    const int* __restrict__ knn_idx,
    const float* __restrict__ W2, const float* __restrict__ b2,
    const float* __restrict__ W3, const float* __restrict__ b3,
    float* __restrict__ out) {
    __shared__ alignas(16) float h1s[80 * 68];
    __shared__ alignas(16) float Ws[64 * 64];
    __shared__ float cs[256];
    __shared__ float mxs[16 * 64];
    __shared__ int idxs[80];

    const int t = threadIdx.x;
    const int p0 = blockIdx.x * 4;
    const int b = p0 >> 12;

    cs[t] = cvec[(size_t)p0 * 64 + t];
    if (t < 80) idxs[t] = knn_idx[(size_t)p0 * KNN + t];
    for (int i = t; i < 4096; i += 256) Ws[i] = W2[i];
    __syncthreads();

    {   // h1 = lrelu(c_i + u_j)
        const int wave = t >> 6, lane = t & 63;
        for (int e = wave; e < 80; e += 4) {
            const int j = idxs[e];
            const float val = u[((size_t)(b << 12) + j) * 64 + lane];
            const float pre = cs[(e / 20) * 64 + lane] + val;
            h1s[e * 68 + lane] = (pre > 0.f) ? pre : SLOPE * pre;
        }
    }
    __syncthreads();

    float acc[5][4];
    gemm_acc(h1s, Ws, b2, acc, t);      // GEMM1
    __syncthreads();

    {   // write h2 back into h1s; stage W3
        const int rg = t >> 4, og = t & 15;
        #pragma unroll
        for (int rr = 0; rr < 5; ++rr)
            #pragma unroll
            for (int oc = 0; oc < 4; ++oc) {
                float v = acc[rr][oc];
                v = (v > 0.f) ? v : SLOPE * v;
                h1s[(5 * rg + rr) * 68 + 4 * og + oc] = v;
            }
        for (int i = t; i < 4096; i += 256) Ws[i] = W3[i];
    }
    __syncthreads();

    gemm_acc(h1s, Ws, b3, acc, t);      // GEMM2
    {   // max over each thread's 5 rows (within one point: 20 % 5 == 0)
        const int rg = t >> 4, og = t & 15;
        #pragma unroll
        for (int oc = 0; oc < 4; ++oc) {
            float m = -1e30f;
            #pragma unroll
            for (int rr = 0; rr < 5; ++rr) {
                float v = acc[rr][oc];
                v = (v > 0.f) ? v : SLOPE * v;
                m = fmaxf(m, v);
            }
            mxs[rg * 64 + 4 * og + oc] = m;
        }
    }
    __syncthreads();

    const int p = t >> 6, col = t & 63;
    const float m = fmaxf(fmaxf(mxs[(4 * p + 0) * 64 + col], mxs[(4 * p + 1) * 64 + col]),
                          fmaxf(mxs[(4 * p + 2) * 64 + col], mxs[(4 * p + 3) * 64 + col]));
    out[(size_t)(p0 + p) * 64 + col] = m;
}

// ---------------------------------------------------------------------------
extern "C" void kernel_launch(void* const* d_in, const int* in_sizes, int n_in,
                              void* d_out, int out_size, void* d_ws, size_t ws_size,
                              hipStream_t stream) {
    const float* pos = (const float*)d_in[0];
    const float* w11 = (const float*)d_in[1];  const float* b11 = (const float*)d_in[2];
    const float* w12 = (const float*)d_in[3];  const float* b12 = (const float*)d_in[4];
    const float* w13 = (const float*)d_in[5];  const float* b13 = (const float*)d_in[6];
    const float* w21 = (const float*)d_in[7];  const float* b21 = (const float*)d_in[8];
    const float* w22 = (const float*)d_in[9];  const float* b22 = (const float*)d_in[10];
    const float* w23 = (const float*)d_in[11]; const float* b23 = (const float*)d_in[12];
    const float* w31 = (const float*)d_in[13]; const float* b31 = (const float*)d_in[14];
    const float* w32 = (const float*)d_in[15]; const float* b32 = (const float*)d_in[16];
    const float* w33 = (const float*)d_in[17]; const float* b33 = (const float*)d_in[18];

    const int BN = BATCH * NPTS;   // 32768
    // Workspace layout: [sqb][idx][x1][u][c][x2], 36.3 MB envelope (R4/R5-proven).
    // part = NSPLIT*KNN*BN u32 = 21.0 MB, aliased per-conv onto DEAD buffers:
    //   conv1/conv3: part at x1 (spans x1,u,c = 25.2 MB; knn input pos/x2 disjoint)
    //   conv2:       part at u  (spans u,c,x2 = 25.2 MB; x1 is the live input)
    // Per conv: knn2 writes part -> merge re-ranks part into idx ->
    // uc overwrites u,c -> edge writes x1/x2/out.
    float* ws = (float*)d_ws;
    float* sqb = ws;                                  // [BN]
    int*   idx = (int*)(sqb + BN);                    // [BN][20]
    float* x1  = (float*)(idx + (size_t)BN * KNN);    // [BN][64]
    float* ubuf = x1 + (size_t)BN * 64;               // [BN][64]
    float* cbuf = ubuf + (size_t)BN * 64;             // [BN][64]
    float* x2  = cbuf + (size_t)BN * 64;              // [BN][64]
    unsigned* part13 = (unsigned*)x1;                 // conv1/conv3 partials
    unsigned* part2  = (unsigned*)ubuf;               // conv2 partials

    const dim3 knn_grid(NPTS / KTHR, NSPLIT, BATCH);  // (64, 8, 8) = 4096 blocks

    // ---- EdgeConv 1 (D=3)
    sq_kernel<3><<<BN / 256, 256, 0, stream>>>(pos, sqb);
    knn2_kernel<3><<<knn_grid, KTHR, 0, stream>>>(pos, sqb, part13);
    merge_kernel<3><<<BN / 64, 256, 0, stream>>>(pos, sqb, part13, idx);
    uc_kernel<3><<<BN / 16, 256, 0, stream>>>(pos, w11, b11, ubuf, cbuf);
    edge_kernel<<<BN / 4, 256, 0, stream>>>(ubuf, cbuf, idx, w12, b12, w13, b13, x1);

    // ---- EdgeConv 2 (D=64)
    sq_kernel<64><<<BN / 256, 256, 0, stream>>>(x1, sqb);
    knn2_kernel<64><<<knn_grid, KTHR, 0, stream>>>(x1, sqb, part2);
    merge_kernel<64><<<BN / 64, 256, 0, stream>>>(x1, sqb, part2, idx);
    uc_kernel<64><<<BN / 16, 256, 0, stream>>>(x1, w21, b21, ubuf, cbuf);
    edge_kernel<<<BN / 4, 256, 0, stream>>>(ubuf, cbuf, idx, w22, b22, w23, b23, x2);

    // ---- EdgeConv 3 (D=64)
    sq_kernel<64><<<BN / 256, 256, 0, stream>>>(x2, sqb);
    knn2_kernel<64><<<knn_grid, KTHR, 0, stream>>>(x2, sqb, part13);
    merge_kernel<64><<<BN / 64, 256, 0, stream>>>(x2, sqb, part13, idx);
    uc_kernel<64><<<BN / 16, 256, 0, stream>>>(x2, w31, b31, ubuf, cbuf);
    edge_kernel<<<BN / 4, 256, 0, stream>>>(ubuf, cbuf, idx, w32, b32, w33, b33, (float*)d_out);
}

// Round 7
// 2803.786 us; speedup vs baseline: 6.6457x; 1.8899x over previous
//
#include <hip/hip_runtime.h>
#include <stdint.h>

#define BATCH 8
#define NPTS 4096
#define KNN 20
#define TILE 64
#define NTILES (NPTS / TILE)              // 64: full scan, no splits
#define BTHR 256                          // knn block threads (64 queries)
#define CAP 4                             // FIFO flush trigger
#define CAPMAX 8                          // FIFO capacity (CAP-1+4 <= 8)
constexpr float SLOPE = 0.2f;

typedef unsigned long long u64;
// hi word unpacks to FLT_MAX (finite, NOT NaN) -> threshold stays permissive
// until the list holds 20 real entries. (R2 lesson: NaN kills the filter.)
#define INIT_KEY 0xFF7FFFFFFFFFFFFFULL

// ---------------------------------------------------------------------------
// squared norms
// ---------------------------------------------------------------------------
template<int D>
__global__ __launch_bounds__(256) void sq_kernel(const float* __restrict__ X,
                                                 float* __restrict__ sq) {
    const int i = blockIdx.x * 256 + threadIdx.x;
    if constexpr (D == 3) {
        const float* p = X + (size_t)i * 3;
        sq[i] = p[0] * p[0] + p[1] * p[1] + p[2] * p[2];
    } else {
        const float4* p = (const float4*)(X + (size_t)i * 64);
        float s = 0.f;
        #pragma unroll
        for (int k = 0; k < 16; ++k) {
            float4 v = p[k];
            s += v.x * v.x; s += v.y * v.y; s += v.z * v.z; s += v.w * v.w;
        }
        sq[i] = s;
    }
}

// ---------------------------------------------------------------------------
// key packing: monotone float bits << 32 | j  (min == nearest, ties -> low j)
// ---------------------------------------------------------------------------
__device__ __forceinline__ u64 pack_key(float d, unsigned j) {
    unsigned ub = __float_as_uint(d);
    ub = (ub & 0x80000000u) ? ~ub : (ub | 0x80000000u);
    return ((u64)ub << 32) | j;
}
__device__ __forceinline__ float key_hi_to_d(unsigned hi) {
    unsigned u = (hi & 0x80000000u) ? (hi ^ 0x80000000u) : ~hi;
    return __uint_as_float(u);
}
__device__ __forceinline__ void insert_key(u64 (&lst)[KNN], u64 c) {
    #pragma unroll
    for (int k = 0; k < KNN; ++k) {
        const u64 lo = (lst[k] < c) ? lst[k] : c;
        const u64 hi = (lst[k] < c) ? c : lst[k];
        lst[k] = lo; c = hi;
    }
}
__device__ __forceinline__ void flush_buf(u64 (&lst)[KNN], const u64* __restrict__ buf,
                                          int t, int& cnt, float& tmax) {
    for (int i = 0; i < CAPMAX; ++i) {
        if (i < cnt) {
            const u64 key = buf[i * BTHR + t];
            if (key < lst[KNN - 1]) insert_key(lst, key);
        }
    }
    cnt = 0;
    tmax = key_hi_to_d((unsigned)(lst[KNN - 1] >> 32));
}

// ---------------------------------------------------------------------------
// kNN v3: R1's 4x4-microtile distance GEMM (16 fmaf per ds_read) + R4's
// threshold/FIFO selection with wave-uniform flush. Full candidate scan per
// block (no splits, no merge kernel). Staging of tile t+1 overlaps phase B
// of tile t. 256 threads / 64 queries per block; grid (NPTS/64, BATCH).
// Phase A: thread (qg=t>>4, jg=t&15) computes dist[4qg..][4jg..] via k-chunk
//          loop; xq reads are quarter-wave broadcast; xj chunk-XOR-swizzled.
// Phase B: thread (q=t>>2, s=t&3) scans 16 dist cols, FIFO+flush.
// Merge:   4 sorted per-slice lists -> global top-20 (exact; ties low-j).
// ---------------------------------------------------------------------------
template<int D>   // 3 or 64
__global__ __launch_bounds__(BTHR) void knn3_kernel(
    const float* __restrict__ X, const float* __restrict__ sq,
    int* __restrict__ knn_idx)        // [B*N][20]
{
    // LDS plan (floats): xq[64*68] | xj[64*68] | dist[64*68] | sqq[64] |
    // sqj[64] | buf[CAPMAX*256 u64 = 4096 floats]  -> 69,120 B total.
    // After the scan, lists[256*20 u64] aliases xq/xj/dist (40,960 B).
    __shared__ alignas(16) float smem[17280];
    float* xq   = smem;
    float* xj   = smem + 4352;
    float* dist = smem + 8704;
    float* sqq  = smem + 13056;
    float* sqj  = smem + 13120;
    u64*   buf  = (u64*)(smem + 13184);
    u64*   lists = (u64*)smem;

    const int t = threadIdx.x;
    const int b = blockIdx.y;
    const int qbase = blockIdx.x * 64;
    const float* Xb  = X  + (size_t)b * NPTS * D;
    const float* sqb = sq + (size_t)b * NPTS;

    const int qg = t >> 4, jg = t & 15;   // phase A mapping
    const int q  = t >> 2, s  = t & 3;    // phase B mapping

    // ---- stage query tile (+ tile 0 of candidates)
    float4 aq[(D == 3) ? 4 : 1];          // D=3: 4 query rows in regs
    float sqq_r[4];
    if constexpr (D == 3) {
        #pragma unroll
        for (int rr = 0; rr < 4; ++rr) {
            const float* qp = Xb + (size_t)(qbase + 4 * qg + rr) * 3;
            aq[rr].x = qp[0]; aq[rr].y = qp[1]; aq[rr].z = qp[2]; aq[rr].w = 0.f;
            sqq_r[rr] = sqb[qbase + 4 * qg + rr];
        }
        if (t < 64) {
            const float* row = Xb + (size_t)t * 3;     // tile 0 = rows 0..63
            xj[0 * 68 + t] = row[0];
            xj[1 * 68 + t] = row[1];
            xj[2 * 68 + t] = row[2];
            sqj[t] = sqb[t];
        }
    } else {
        #pragma unroll
        for (int ci = t; ci < 1024; ci += BTHR) {
            const int r = ci >> 4, c4 = ci & 15;
            *(float4*)&xq[r * 68 + 4 * c4] =
                *(const float4*)&Xb[(size_t)(qbase + r) * 64 + 4 * c4];
        }
        #pragma unroll
        for (int ci = t; ci < 1024; ci += BTHR) {
            const int r = ci >> 4, c4 = ci & 15;
            const int c4s = c4 ^ ((r >> 2) & 3);       // chunk swizzle
            *(float4*)&xj[r * 68 + 4 * c4s] =
                *(const float4*)&Xb[(size_t)r * 64 + 4 * c4];   // tile 0
        }
        if (t < 64) { sqq[t] = sqb[qbase + t]; sqj[t] = sqb[t]; }
    }
    __syncthreads();
    if constexpr (D != 3) {
        #pragma unroll
        for (int rr = 0; rr < 4; ++rr) sqq_r[rr] = sqq[4 * qg + rr];  // broadcast
    }

    u64 lst[KNN];
    #pragma unroll
    for (int k = 0; k < KNN; ++k) lst[k] = INIT_KEY;
    float tmax = 3.402823466e38f;
    int cnt = 0;

    for (int tile = 0; tile < NTILES; ++tile) {
        // ---- phase A: 4x4 micro-tile distances -> dist LDS
        if constexpr (D == 3) {
            float sj[4];
            #pragma unroll
            for (int cc = 0; cc < 4; ++cc) sj[cc] = sqj[4 * jg + cc];
            float4 bx, by, bz;
            bx.x = xj[0 * 68 + 4 * jg + 0]; bx.y = xj[0 * 68 + 4 * jg + 1];
            bx.z = xj[0 * 68 + 4 * jg + 2]; bx.w = xj[0 * 68 + 4 * jg + 3];
            by.x = xj[1 * 68 + 4 * jg + 0]; by.y = xj[1 * 68 + 4 * jg + 1];
            by.z = xj[1 * 68 + 4 * jg + 2]; by.w = xj[1 * 68 + 4 * jg + 3];
            bz.x = xj[2 * 68 + 4 * jg + 0]; bz.y = xj[2 * 68 + 4 * jg + 1];
            bz.z = xj[2 * 68 + 4 * jg + 2]; bz.w = xj[2 * 68 + 4 * jg + 3];
            #pragma unroll
            for (int rr = 0; rr < 4; ++rr) {
                float4 dv;
                dv.x = sqq_r[rr] + sj[0] - 2.f * (aq[rr].x * bx.x + aq[rr].y * by.x + aq[rr].z * bz.x);
                dv.y = sqq_r[rr] + sj[1] - 2.f * (aq[rr].x * bx.y + aq[rr].y * by.y + aq[rr].z * bz.y);
                dv.z = sqq_r[rr] + sj[2] - 2.f * (aq[rr].x * bx.z + aq[rr].y * by.z + aq[rr].z * bz.z);
                dv.w = sqq_r[rr] + sj[3] - 2.f * (aq[rr].x * bx.w + aq[rr].y * by.w + aq[rr].z * bz.w);
                *(float4*)&dist[(4 * qg + rr) * 68 + 4 * jg] = dv;
            }
        } else {
            float acc[4][4];
            #pragma unroll
            for (int rr = 0; rr < 4; ++rr)
                #pragma unroll
                for (int cc = 0; cc < 4; ++cc) acc[rr][cc] = 0.f;
            #pragma unroll
            for (int k = 0; k < 16; ++k) {
                float4 a[4], bv[4];
                #pragma unroll
                for (int rr = 0; rr < 4; ++rr)
                    a[rr] = *(const float4*)&xq[(4 * qg + rr) * 68 + 4 * k];
                const int kx = k ^ (jg & 3);
                #pragma unroll
                for (int cc = 0; cc < 4; ++cc)
                    bv[cc] = *(const float4*)&xj[(4 * jg + cc) * 68 + 4 * kx];
                #pragma unroll
                for (int rr = 0; rr < 4; ++rr)
                    #pragma unroll
                    for (int cc = 0; cc < 4; ++cc) {
                        float v = acc[rr][cc];
                        v = fmaf(a[rr].x, bv[cc].x, v);
                        v = fmaf(a[rr].y, bv[cc].y, v);
                        v = fmaf(a[rr].z, bv[cc].z, v);
                        v = fmaf(a[rr].w, bv[cc].w, v);
                        acc[rr][cc] = v;
                    }
            }
            float sj[4];
            #pragma unroll
            for (int cc = 0; cc < 4; ++cc) sj[cc] = sqj[4 * jg + cc];
            #pragma unroll
            for (int rr = 0; rr < 4; ++rr) {
                float4 dv;
                dv.x = sqq_r[rr] + sj[0] - 2.f * acc[rr][0];
                dv.y = sqq_r[rr] + sj[1] - 2.f * acc[rr][1];
                dv.z = sqq_r[rr] + sj[2] - 2.f * acc[rr][2];
                dv.w = sqq_r[rr] + sj[3] - 2.f * acc[rr][3];
                *(float4*)&dist[(4 * qg + rr) * 68 + 4 * jg] = dv;
            }
        }
        __syncthreads();   // dist ready; xj consumed

        // ---- stage NEXT candidate tile (overlaps phase B; xj != dist)
        if (tile + 1 < NTILES) {
            const int cb = (tile + 1) * TILE;
            if constexpr (D == 3) {
                if (t < 64) {
                    const float* row = Xb + (size_t)(cb + t) * 3;
                    xj[0 * 68 + t] = row[0];
                    xj[1 * 68 + t] = row[1];
                    xj[2 * 68 + t] = row[2];
                    sqj[t] = sqb[cb + t];
                }
            } else {
                #pragma unroll
                for (int ci = t; ci < 1024; ci += BTHR) {
                    const int r = ci >> 4, c4 = ci & 15;
                    const int c4s = c4 ^ ((r >> 2) & 3);
                    *(float4*)&xj[r * 68 + 4 * c4s] =
                        *(const float4*)&Xb[(size_t)(cb + r) * 64 + 4 * c4];
                }
                if (t < 64) sqj[t] = sqb[cb + t];
            }
        }

        // ---- phase B: threshold + FIFO over this thread's 16 dist cols
        {
            const int cbase = tile * TILE;
            const float* drow = &dist[q * 68 + s * 16];
            #pragma unroll
            for (int g = 0; g < 4; ++g) {
                #pragma unroll
                for (int i = 0; i < 4; ++i) {
                    const float dd = drow[g * 4 + i];
                    if (dd <= tmax) {
                        buf[cnt * BTHR + t] = pack_key(dd, cbase + s * 16 + g * 4 + i);
                        ++cnt;
                    }
                }
                // wave-uniform flush; max +4 since last check -> cnt <= 7 < 8
                if (__any(cnt >= CAP)) flush_buf(lst, buf, t, cnt, tmax);
            }
        }
        __syncthreads();   // dist consumed; xj ready for next phase A
    }
    if (__any(cnt > 0)) flush_buf(lst, buf, t, cnt, tmax);

    // ---- merge: 4 sorted slice-lists per query -> exact top-20
    #pragma unroll
    for (int k = 0; k < KNN; ++k) lists[t * KNN + k] = lst[k];   // aliases xq/xj/dist
    __syncthreads();

    if (t < 64) {
        const u64* L0 = lists + (size_t)(t * 4 + 0) * KNN;
        const u64* L1 = L0 + KNN;
        const u64* L2 = L1 + KNN;
        const u64* L3 = L2 + KNN;
        int p0 = 0, p1 = 0, p2 = 0, p3 = 0;
        int* outp = knn_idx + ((size_t)b * NPTS + qbase + t) * KNN;
        for (int k = 0; k < KNN; ++k) {
            const u64 h0 = L0[p0], h1 = L1[p1], h2 = L2[p2], h3 = L3[p3];
            const u64 m01 = (h0 < h1) ? h0 : h1;
            const u64 m23 = (h2 < h3) ? h2 : h3;
            const u64 m   = (m01 < m23) ? m01 : m23;
            outp[k] = (int)(unsigned)(m & 0xffffffffu);
            if (m == h0) ++p0; else if (m == h1) ++p1; else if (m == h2) ++p2; else ++p3;
        }
    }
}

// ---------------------------------------------------------------------------
// per-point u = X @ W1b, c = X @ W1a - u + b1
//   h1(i,j) = lrelu([x_i | x_j-x_i] @ W1 + b1) = lrelu(c_i + u_j)
// ---------------------------------------------------------------------------
template<int D>
__global__ __launch_bounds__(256) void uc_kernel(
    const float* __restrict__ X, const float* __restrict__ W1,
    const float* __restrict__ b1, float* __restrict__ u, float* __restrict__ cvec) {
    __shared__ float Xs[16 * D];
    const int n0 = blockIdx.x * 16;
    const int t = threadIdx.x;
    for (int i = t; i < 16 * D; i += 256)
        Xs[i] = X[(size_t)n0 * D + i];
    __syncthreads();

    const int o = t & 63;
    const int pg = t >> 6;
    float va[4] = {0.f, 0.f, 0.f, 0.f};
    float vb[4] = {0.f, 0.f, 0.f, 0.f};
    for (int d = 0; d < D; ++d) {
        const float wa = W1[d * 64 + o];
        const float wb = W1[(D + d) * 64 + o];
        #pragma unroll
        for (int pi = 0; pi < 4; ++pi) {
            const float x = Xs[(pg * 4 + pi) * D + d];
            va[pi] += x * wa;
            vb[pi] += x * wb;
        }
    }
    const float bo = b1[o];
    #pragma unroll
    for (int pi = 0; pi < 4; ++pi) {
        const size_t n = (size_t)n0 + pg * 4 + pi;
        u[n * 64 + o] = vb[pi];
        cvec[n * 64 + o] = va[pi] - vb[pi] + bo;
    }
}

// ---------------------------------------------------------------------------
// fused edge MLP + max aggregation (single h buffer; acc lives in regs
// across the barrier, h2 written back into h1s; W3 staged after GEMM1)
// ---------------------------------------------------------------------------
__device__ __forceinline__ void gemm_acc(const float* __restrict__ Xs,
                                         const float* __restrict__ Ws,
                                         const float* __restrict__ bias,
                                         float (&acc)[5][4], const int t) {
    const int rg = t >> 4, og = t & 15;
    #pragma unroll
    for (int oc = 0; oc < 4; ++oc) {
        const float bb = bias[4 * og + oc];
        #pragma unroll
        for (int rr = 0; rr < 5; ++rr) acc[rr][oc] = bb;
    }
    #pragma unroll
    for (int k4 = 0; k4 < 16; ++k4) {
        float4 xv[5];
        #pragma unroll
        for (int rr = 0; rr < 5; ++rr)
            xv[rr] = *(const float4*)&Xs[(5 * rg + rr) * 68 + 4 * k4];
        float4 wv[4];
        #pragma unroll
        for (int kk = 0; kk < 4; ++kk)
            wv[kk] = *(const float4*)&Ws[(4 * k4 + kk) * 64 + 4 * og];
        #pragma unroll
        for (int rr = 0; rr < 5; ++rr) {
            acc[rr][0] += xv[rr].x * wv[0].x + xv[rr].y * wv[1].x + xv[rr].z * wv[2].x + xv[rr].w * wv[3].x;
            acc[rr][1] += xv[rr].x * wv[0].y + xv[rr].y * wv[1].y + xv[rr].z * wv[2].y + xv[rr].w * wv[3].y;
            acc[rr][2] += xv[rr].x * wv[0].z + xv[rr].y * wv[1].z + xv[rr].z * wv[2].z + xv[rr].w * wv[3].z;
            acc[rr][3] += xv[rr].x * wv[0].w + xv[rr].y * wv[1].w + xv[rr].z * wv[2].w + xv[rr].w * wv[3].w;
        }
    }
}

__global__ __launch_bounds__(256) void edge_kernel(
    const float* __restrict__ u, const float* __restrict__ cvec,
    const int* __restrict__ knn_idx,
    const float* __restrict__ W2, const float* __restrict__ b2,
    const float* __restrict__ W3, const float* __restrict__ b3,
    float* __restrict__ out) {
    __shared__ alignas(16) float h1s[80 * 68];
    __shared__ alignas(16) float Ws[64 * 64];
    __shared__ float cs[256];
    __shared__ float mxs[16 * 64];
    __shared__ int idxs[80];

    const int t = threadIdx.x;
    const int p0 = blockIdx.x * 4;
    const int b = p0 >> 12;

    cs[t] = cvec[(size_t)p0 * 64 + t];
    if (t < 80) idxs[t] = knn_idx[(size_t)p0 * KNN + t];
    for (int i = t; i < 4096; i += 256) Ws[i] = W2[i];
    __syncthreads();

    {   // h1 = lrelu(c_i + u_j)
        const int wave = t >> 6, lane = t & 63;
        for (int e = wave; e < 80; e += 4) {
            const int j = idxs[e];
            const float val = u[((size_t)(b << 12) + j) * 64 + lane];
            const float pre = cs[(e / 20) * 64 + lane] + val;
            h1s[e * 68 + lane] = (pre > 0.f) ? pre : SLOPE * pre;
        }
    }
    __syncthreads();

    float acc[5][4];
    gemm_acc(h1s, Ws, b2, acc, t);      // GEMM1
    __syncthreads();

    {   // write h2 back into h1s; stage W3
        const int rg = t >> 4, og = t & 15;
        #pragma unroll
        for (int rr = 0; rr < 5; ++rr)
            #pragma unroll
            for (int oc = 0; oc < 4; ++oc) {
                float v = acc[rr][oc];
                v = (v > 0.f) ? v : SLOPE * v;
                h1s[(5 * rg + rr) * 68 + 4 * og + oc] = v;
            }
        for (int i = t; i < 4096; i += 256) Ws[i] = W3[i];
    }
    __syncthreads();

    gemm_acc(h1s, Ws, b3, acc, t);      // GEMM2
    {   // max over each thread's 5 rows (within one point: 20 % 5 == 0)
        const int rg = t >> 4, og = t & 15;
        #pragma unroll
        for (int oc = 0; oc < 4; ++oc) {
            float m = -1e30f;
            #pragma unroll
            for (int rr = 0; rr < 5; ++rr) {
                float v = acc[rr][oc];
                v = (v > 0.f) ? v : SLOPE * v;
                m = fmaxf(m, v);
            }
            mxs[rg * 64 + 4 * og + oc] = m;
        }
    }
    __syncthreads();

    const int p = t >> 6, col = t & 63;
    const float m = fmaxf(fmaxf(mxs[(4 * p + 0) * 64 + col], mxs[(4 * p + 1) * 64 + col]),
                          fmaxf(mxs[(4 * p + 2) * 64 + col], mxs[(4 * p + 3) * 64 + col]));
    out[(size_t)(p0 + p) * 64 + col] = m;
}

// ---------------------------------------------------------------------------
extern "C" void kernel_launch(void* const* d_in, const int* in_sizes, int n_in,
                              void* d_out, int out_size, void* d_ws, size_t ws_size,
                              hipStream_t stream) {
    const float* pos = (const float*)d_in[0];
    const float* w11 = (const float*)d_in[1];  const float* b11 = (const float*)d_in[2];
    const float* w12 = (const float*)d_in[3];  const float* b12 = (const float*)d_in[4];
    const float* w13 = (const float*)d_in[5];  const float* b13 = (const float*)d_in[6];
    const float* w21 = (const float*)d_in[7];  const float* b21 = (const float*)d_in[8];
    const float* w22 = (const float*)d_in[9];  const float* b22 = (const float*)d_in[10];
    const float* w23 = (const float*)d_in[11]; const float* b23 = (const float*)d_in[12];
    const float* w31 = (const float*)d_in[13]; const float* b31 = (const float*)d_in[14];
    const float* w32 = (const float*)d_in[15]; const float* b32 = (const float*)d_in[16];
    const float* w33 = (const float*)d_in[17]; const float* b33 = (const float*)d_in[18];

    const int BN = BATCH * NPTS;   // 32768
    // Simple workspace (no aliasing): [sqb][idx][x1][u][c][x2] = 36.3 MB
    float* ws = (float*)d_ws;
    float* sqb = ws;                                  // [BN]
    int*   idx = (int*)(sqb + BN);                    // [BN][20]
    float* x1  = (float*)(idx + (size_t)BN * KNN);    // [BN][64]
    float* ubuf = x1 + (size_t)BN * 64;               // [BN][64]
    float* cbuf = ubuf + (size_t)BN * 64;             // [BN][64]
    float* x2  = cbuf + (size_t)BN * 64;              // [BN][64]

    const dim3 knn_grid(NPTS / 64, BATCH);            // (64, 8) = 512 blocks

    // ---- EdgeConv 1 (D=3)
    sq_kernel<3><<<BN / 256, 256, 0, stream>>>(pos, sqb);
    knn3_kernel<3><<<knn_grid, BTHR, 0, stream>>>(pos, sqb, idx);
    uc_kernel<3><<<BN / 16, 256, 0, stream>>>(pos, w11, b11, ubuf, cbuf);
    edge_kernel<<<BN / 4, 256, 0, stream>>>(ubuf, cbuf, idx, w12, b12, w13, b13, x1);

    // ---- EdgeConv 2 (D=64)
    sq_kernel<64><<<BN / 256, 256, 0, stream>>>(x1, sqb);
    knn3_kernel<64><<<knn_grid, BTHR, 0, stream>>>(x1, sqb, idx);
    uc_kernel<64><<<BN / 16, 256, 0, stream>>>(x1, w21, b21, ubuf, cbuf);
    edge_kernel<<<BN / 4, 256, 0, stream>>>(ubuf, cbuf, idx, w22, b22, w23, b23, x2);

    // ---- EdgeConv 3 (D=64)
    sq_kernel<64><<<BN / 256, 256, 0, stream>>>(x2, sqb);
    knn3_kernel<64><<<knn_grid, BTHR, 0, stream>>>(x2, sqb, idx);
    uc_kernel<64><<<BN / 16, 256, 0, stream>>>(x2, w31, b31, ubuf, cbuf);
    edge_kernel<<<BN / 4, 256, 0, stream>>>(ubuf, cbuf, idx, w32, b32, w33, b33, (float*)d_out);
}

// Round 8
// 2617.393 us; speedup vs baseline: 7.1190x; 1.0712x over previous
//
#include <hip/hip_runtime.h>
#include <stdint.h>

#define BATCH 8
#define NPTS 4096
#define KNN 20
#define TILE 64
#define NTILES (NPTS / TILE)              // 64: full scan, no splits
#define BTHR 256                          // knn block threads (64 queries)
#define CAP 4                             // FIFO flush trigger
#define CAPMAX 8                          // FIFO capacity (CAP-1+4 <= 8)
constexpr float SLOPE = 0.2f;

typedef unsigned long long u64;
// hi word unpacks to FLT_MAX (finite, NOT NaN) -> threshold stays permissive
// until the list holds 20 real entries. (R2 lesson: NaN kills the filter.)
#define INIT_KEY 0xFF7FFFFFFFFFFFFFULL

// ---------------------------------------------------------------------------
// squared norms
// ---------------------------------------------------------------------------
template<int D>
__global__ __launch_bounds__(256) void sq_kernel(const float* __restrict__ X,
                                                 float* __restrict__ sq) {
    const int i = blockIdx.x * 256 + threadIdx.x;
    if constexpr (D == 3) {
        const float* p = X + (size_t)i * 3;
        sq[i] = p[0] * p[0] + p[1] * p[1] + p[2] * p[2];
    } else {
        const float4* p = (const float4*)(X + (size_t)i * 64);
        float s = 0.f;
        #pragma unroll
        for (int k = 0; k < 16; ++k) {
            float4 v = p[k];
            s += v.x * v.x; s += v.y * v.y; s += v.z * v.z; s += v.w * v.w;
        }
        sq[i] = s;
    }
}

// ---------------------------------------------------------------------------
// key packing: monotone float bits << 32 | j  (min == nearest, ties -> low j)
// ---------------------------------------------------------------------------
__device__ __forceinline__ u64 pack_key(float d, unsigned j) {
    unsigned ub = __float_as_uint(d);
    ub = (ub & 0x80000000u) ? ~ub : (ub | 0x80000000u);
    return ((u64)ub << 32) | j;
}
__device__ __forceinline__ float key_hi_to_d(unsigned hi) {
    unsigned u = (hi & 0x80000000u) ? (hi ^ 0x80000000u) : ~hi;
    return __uint_as_float(u);
}
__device__ __forceinline__ void insert_key(u64 (&lst)[KNN], u64 c) {
    #pragma unroll
    for (int k = 0; k < KNN; ++k) {
        const u64 lo = (lst[k] < c) ? lst[k] : c;
        const u64 hi = (lst[k] < c) ? c : lst[k];
        lst[k] = lo; c = hi;
    }
}
__device__ __forceinline__ void flush_buf(u64 (&lst)[KNN], const u64* __restrict__ buf,
                                          int t, int& cnt, float& tmax) {
    for (int i = 0; i < CAPMAX; ++i) {
        if (i < cnt) {
            const u64 key = buf[i * BTHR + t];
            if (key < lst[KNN - 1]) insert_key(lst, key);
        }
    }
    cnt = 0;
    tmax = key_hi_to_d((unsigned)(lst[KNN - 1] >> 32));
}

// ---------------------------------------------------------------------------
// kNN v3.1: 4x4-microtile distance GEMM + threshold/FIFO selection.
// Bank-conflict fixes vs v3 (1.15e8 conflict cycles = 27% of kernel):
//  * xj columns stored ROTATED by row>>2 (additive swizzle; XOR cancels
//    against the additive bank function row+col):  col4' = (c4+(r>>2))&15,
//    read kx = (k+jg)&15  -> 2 addrs/bank-group (conflict-free b128).
//  * phase B reads dist as float4 (group = (q+4s+g) mod 8 -> optimal 8/group).
// Distance math is bit-identical to v3 (same logical k order, same chains).
// ---------------------------------------------------------------------------
template<int D>   // 3 or 64
__global__ __launch_bounds__(BTHR) void knn3_kernel(
    const float* __restrict__ X, const float* __restrict__ sq,
    int* __restrict__ knn_idx)        // [B*N][20]
{
    // LDS (floats): xq[64*68] | xj[64*68] | dist[64*68] | sqq[64] | sqj[64]
    //               | buf[8*256 u64]  -> 69,120 B. lists aliases xq afterwards.
    __shared__ alignas(16) float smem[17280];
    float* xq   = smem;
    float* xj   = smem + 4352;
    float* dist = smem + 8704;
    float* sqq  = smem + 13056;
    float* sqj  = smem + 13120;
    u64*   buf  = (u64*)(smem + 13184);
    u64*   lists = (u64*)smem;

    const int t = threadIdx.x;
    const int b = blockIdx.y;
    const int qbase = blockIdx.x * 64;
    const float* Xb  = X  + (size_t)b * NPTS * D;
    const float* sqb = sq + (size_t)b * NPTS;

    const int qg = t >> 4, jg = t & 15;   // phase A mapping
    const int q  = t >> 2, s  = t & 3;    // phase B mapping

    // ---- stage query tile (+ tile 0 of candidates)
    float4 aq[(D == 3) ? 4 : 1];          // D=3: 4 query rows in regs
    float sqq_r[4];
    if constexpr (D == 3) {
        #pragma unroll
        for (int rr = 0; rr < 4; ++rr) {
            const float* qp = Xb + (size_t)(qbase + 4 * qg + rr) * 3;
            aq[rr].x = qp[0]; aq[rr].y = qp[1]; aq[rr].z = qp[2]; aq[rr].w = 0.f;
            sqq_r[rr] = sqb[qbase + 4 * qg + rr];
        }
        if (t < 64) {
            const float* row = Xb + (size_t)t * 3;     // tile 0 = rows 0..63
            xj[0 * 68 + t] = row[0];
            xj[1 * 68 + t] = row[1];
            xj[2 * 68 + t] = row[2];
            sqj[t] = sqb[t];
        }
    } else {
        #pragma unroll
        for (int ci = t; ci < 1024; ci += BTHR) {
            const int r = ci >> 4, c4 = ci & 15;
            *(float4*)&xq[r * 68 + 4 * c4] =
                *(const float4*)&Xb[(size_t)(qbase + r) * 64 + 4 * c4];
        }
        #pragma unroll
        for (int ci = t; ci < 1024; ci += BTHR) {
            const int r = ci >> 4, c4 = ci & 15;
            const int c4s = (c4 + (r >> 2)) & 15;      // additive rotation
            *(float4*)&xj[r * 68 + 4 * c4s] =
                *(const float4*)&Xb[(size_t)r * 64 + 4 * c4];   // tile 0
        }
        if (t < 64) { sqq[t] = sqb[qbase + t]; sqj[t] = sqb[t]; }
    }
    __syncthreads();
    if constexpr (D != 3) {
        #pragma unroll
        for (int rr = 0; rr < 4; ++rr) sqq_r[rr] = sqq[4 * qg + rr];  // broadcast
    }

    u64 lst[KNN];
    #pragma unroll
    for (int k = 0; k < KNN; ++k) lst[k] = INIT_KEY;
    float tmax = 3.402823466e38f;
    int cnt = 0;

    for (int tile = 0; tile < NTILES; ++tile) {
        // ---- phase A: 4x4 micro-tile distances -> dist LDS
        if constexpr (D == 3) {
            float sj[4];
            #pragma unroll
            for (int cc = 0; cc < 4; ++cc) sj[cc] = sqj[4 * jg + cc];
            float4 bx, by, bz;
            bx.x = xj[0 * 68 + 4 * jg + 0]; bx.y = xj[0 * 68 + 4 * jg + 1];
            bx.z = xj[0 * 68 + 4 * jg + 2]; bx.w = xj[0 * 68 + 4 * jg + 3];
            by.x = xj[1 * 68 + 4 * jg + 0]; by.y = xj[1 * 68 + 4 * jg + 1];
            by.z = xj[1 * 68 + 4 * jg + 2]; by.w = xj[1 * 68 + 4 * jg + 3];
            bz.x = xj[2 * 68 + 4 * jg + 0]; bz.y = xj[2 * 68 + 4 * jg + 1];
            bz.z = xj[2 * 68 + 4 * jg + 2]; bz.w = xj[2 * 68 + 4 * jg + 3];
            #pragma unroll
            for (int rr = 0; rr < 4; ++rr) {
                float4 dv;
                dv.x = sqq_r[rr] + sj[0] - 2.f * (aq[rr].x * bx.x + aq[rr].y * by.x + aq[rr].z * bz.x);
                dv.y = sqq_r[rr] + sj[1] - 2.f * (aq[rr].x * bx.y + aq[rr].y * by.y + aq[rr].z * bz.y);
                dv.z = sqq_r[rr] + sj[2] - 2.f * (aq[rr].x * bx.z + aq[rr].y * by.z + aq[rr].z * bz.z);
                dv.w = sqq_r[rr] + sj[3] - 2.f * (aq[rr].x * bx.w + aq[rr].y * by.w + aq[rr].z * bz.w);
                *(float4*)&dist[(4 * qg + rr) * 68 + 4 * jg] = dv;
            }
        } else {
            float acc[4][4];
            #pragma unroll
            for (int rr = 0; rr < 4; ++rr)
                #pragma unroll
                for (int cc = 0; cc < 4; ++cc) acc[rr][cc] = 0.f;
            #pragma unroll
            for (int k = 0; k < 16; ++k) {
                float4 a[4], bv[4];
                #pragma unroll
                for (int rr = 0; rr < 4; ++rr)
                    a[rr] = *(const float4*)&xq[(4 * qg + rr) * 68 + 4 * k];
                const int kx = (k + jg) & 15;          // rotated read
                #pragma unroll
                for (int cc = 0; cc < 4; ++cc)
                    bv[cc] = *(const float4*)&xj[(4 * jg + cc) * 68 + 4 * kx];
                #pragma unroll
                for (int rr = 0; rr < 4; ++rr)
                    #pragma unroll
                    for (int cc = 0; cc < 4; ++cc) {
                        float v = acc[rr][cc];
                        v = fmaf(a[rr].x, bv[cc].x, v);
                        v = fmaf(a[rr].y, bv[cc].y, v);
                        v = fmaf(a[rr].z, bv[cc].z, v);
                        v = fmaf(a[rr].w, bv[cc].w, v);
                        acc[rr][cc] = v;
                    }
            }
            float sj[4];
            #pragma unroll
            for (int cc = 0; cc < 4; ++cc) sj[cc] = sqj[4 * jg + cc];
            #pragma unroll
            for (int rr = 0; rr < 4; ++rr) {
                float4 dv;
                dv.x = sqq_r[rr] + sj[0] - 2.f * acc[rr][0];
                dv.y = sqq_r[rr] + sj[1] - 2.f * acc[rr][1];
                dv.z = sqq_r[rr] + sj[2] - 2.f * acc[rr][2];
                dv.w = sqq_r[rr] + sj[3] - 2.f * acc[rr][3];
                *(float4*)&dist[(4 * qg + rr) * 68 + 4 * jg] = dv;
            }
        }
        __syncthreads();   // dist ready; xj consumed

        // ---- stage NEXT candidate tile (overlaps phase B; xj != dist)
        if (tile + 1 < NTILES) {
            const int cb = (tile + 1) * TILE;
            if constexpr (D == 3) {
                if (t < 64) {
                    const float* row = Xb + (size_t)(cb + t) * 3;
                    xj[0 * 68 + t] = row[0];
                    xj[1 * 68 + t] = row[1];
                    xj[2 * 68 + t] = row[2];
                    sqj[t] = sqb[cb + t];
                }
            } else {
                #pragma unroll
                for (int ci = t; ci < 1024; ci += BTHR) {
                    const int r = ci >> 4, c4 = ci & 15;
                    const int c4s = (c4 + (r >> 2)) & 15;
                    *(float4*)&xj[r * 68 + 4 * c4s] =
                        *(const float4*)&Xb[(size_t)(cb + r) * 64 + 4 * c4];
                }
                if (t < 64) sqj[t] = sqb[cb + t];
            }
        }

        // ---- phase B: threshold + FIFO over this thread's 16 dist cols
        {
            const int cbase = tile * TILE;
            const float* drow = &dist[q * 68 + s * 16];
            #pragma unroll
            for (int g = 0; g < 4; ++g) {
                const float4 dv = *(const float4*)&drow[g * 4];   // vector read
                const float dd0 = dv.x, dd1 = dv.y, dd2 = dv.z, dd3 = dv.w;
                if (dd0 <= tmax) { buf[cnt * BTHR + t] = pack_key(dd0, cbase + s * 16 + g * 4 + 0); ++cnt; }
                if (dd1 <= tmax) { buf[cnt * BTHR + t] = pack_key(dd1, cbase + s * 16 + g * 4 + 1); ++cnt; }
                if (dd2 <= tmax) { buf[cnt * BTHR + t] = pack_key(dd2, cbase + s * 16 + g * 4 + 2); ++cnt; }
                if (dd3 <= tmax) { buf[cnt * BTHR + t] = pack_key(dd3, cbase + s * 16 + g * 4 + 3); ++cnt; }
                // wave-uniform flush; max +4 since last check -> cnt <= 7 < 8
                if (__any(cnt >= CAP)) flush_buf(lst, buf, t, cnt, tmax);
            }
        }
        __syncthreads();   // dist consumed; xj ready for next phase A
    }
    if (__any(cnt > 0)) flush_buf(lst, buf, t, cnt, tmax);

    // ---- merge: 4 sorted slice-lists per query -> exact top-20
    #pragma unroll
    for (int k = 0; k < KNN; ++k) lists[t * KNN + k] = lst[k];   // aliases xq/xj/dist
    __syncthreads();

    if (t < 64) {
        const u64* L0 = lists + (size_t)(t * 4 + 0) * KNN;
        const u64* L1 = L0 + KNN;
        const u64* L2 = L1 + KNN;
        const u64* L3 = L2 + KNN;
        int p0 = 0, p1 = 0, p2 = 0, p3 = 0;
        int* outp = knn_idx + ((size_t)b * NPTS + qbase + t) * KNN;
        for (int k = 0; k < KNN; ++k) {
            const u64 h0 = L0[p0], h1 = L1[p1], h2 = L2[p2], h3 = L3[p3];
            const u64 m01 = (h0 < h1) ? h0 : h1;
            const u64 m23 = (h2 < h3) ? h2 : h3;
            const u64 m   = (m01 < m23) ? m01 : m23;
            outp[k] = (int)(unsigned)(m & 0xffffffffu);
            if (m == h0) ++p0; else if (m == h1) ++p1; else if (m == h2) ++p2; else ++p3;
        }
    }
}

// ---------------------------------------------------------------------------
// per-point u = X @ W1b, c = X @ W1a - u + b1
//   h1(i,j) = lrelu([x_i | x_j-x_i] @ W1 + b1) = lrelu(c_i + u_j)
// ---------------------------------------------------------------------------
template<int D>
__global__ __launch_bounds__(256) void uc_kernel(
    const float* __restrict__ X, const float* __restrict__ W1,
    const float* __restrict__ b1, float* __restrict__ u, float* __restrict__ cvec) {
    __shared__ float Xs[16 * D];
    const int n0 = blockIdx.x * 16;
    const int t = threadIdx.x;
    for (int i = t; i < 16 * D; i += 256)
        Xs[i] = X[(size_t)n0 * D + i];
    __syncthreads();

    const int o = t & 63;
    const int pg = t >> 6;
    float va[4] = {0.f, 0.f, 0.f, 0.f};
    float vb[4] = {0.f, 0.f, 0.f, 0.f};
    for (int d = 0; d < D; ++d) {
        const float wa = W1[d * 64 + o];
        const float wb = W1[(D + d) * 64 + o];
        #pragma unroll
        for (int pi = 0; pi < 4; ++pi) {
            const float x = Xs[(pg * 4 + pi) * D + d];
            va[pi] += x * wa;
            vb[pi] += x * wb;
        }
    }
    const float bo = b1[o];
    #pragma unroll
    for (int pi = 0; pi < 4; ++pi) {
        const size_t n = (size_t)n0 + pg * 4 + pi;
        u[n * 64 + o] = vb[pi];
        cvec[n * 64 + o] = va[pi] - vb[pi] + bo;
    }
}

// ---------------------------------------------------------------------------
// fused edge MLP + max aggregation (single h buffer; acc lives in regs
// across the barrier, h2 written back into h1s; W3 staged after GEMM1)
// ---------------------------------------------------------------------------
__device__ __forceinline__ void gemm_acc(const float* __restrict__ Xs,
                                         const float* __restrict__ Ws,
                                         const float* __restrict__ bias,
                                         float (&acc)[5][4], const int t) {
    const int rg = t >> 4, og = t & 15;
    #pragma unroll
    for (int oc = 0; oc < 4; ++oc) {
        const float bb = bias[4 * og + oc];
        #pragma unroll
        for (int rr = 0; rr < 5; ++rr) acc[rr][oc] = bb;
    }
    #pragma unroll
    for (int k4 = 0; k4 < 16; ++k4) {
        float4 xv[5];
        #pragma unroll
        for (int rr = 0; rr < 5; ++rr)
            xv[rr] = *(const float4*)&Xs[(5 * rg + rr) * 68 + 4 * k4];
        float4 wv[4];
        #pragma unroll
        for (int kk = 0; kk < 4; ++kk)
            wv[kk] = *(const float4*)&Ws[(4 * k4 + kk) * 64 + 4 * og];
        #pragma unroll
        for (int rr = 0; rr < 5; ++rr) {
            acc[rr][0] += xv[rr].x * wv[0].x + xv[rr].y * wv[1].x + xv[rr].z * wv[2].x + xv[rr].w * wv[3].x;
            acc[rr][1] += xv[rr].x * wv[0].y + xv[rr].y * wv[1].y + xv[rr].z * wv[2].y + xv[rr].w * wv[3].y;
            acc[rr][2] += xv[rr].x * wv[0].z + xv[rr].y * wv[1].z + xv[rr].z * wv[2].z + xv[rr].w * wv[3].z;
            acc[rr][3] += xv[rr].x * wv[0].w + xv[rr].y * wv[1].w + xv[rr].z * wv[2].w + xv[rr].w * wv[3].w;
        }
    }
}

__global__ __launch_bounds__(256) void edge_kernel(
    const float* __restrict__ u, const float* __restrict__ cvec,
    const int* __restrict__ knn_idx,
    const float* __restrict__ W2, const float* __restrict__ b2,
    const float* __restrict__ W3, const float* __restrict__ b3,
    float* __restrict__ out) {
    __shared__ alignas(16) float h1s[80 * 68];
    __shared__ alignas(16) float Ws[64 * 64];
    __shared__ float cs[256];
    __shared__ float mxs[16 * 64];
    __shared__ int idxs[80];

    const int t = threadIdx.x;
    const int p0 = blockIdx.x * 4;
    const int b = p0 >> 12;

    cs[t] = cvec[(size_t)p0 * 64 + t];
    if (t < 80) idxs[t] = knn_idx[(size_t)p0 * KNN + t];
    for (int i = t; i < 4096; i += 256) Ws[i] = W2[i];
    __syncthreads();

    {   // h1 = lrelu(c_i + u_j)
        const int wave = t >> 6, lane = t & 63;
        for (int e = wave; e < 80; e += 4) {
            const int j = idxs[e];
            const float val = u[((size_t)(b << 12) + j) * 64 + lane];
            const float pre = cs[(e / 20) * 64 + lane] + val;
            h1s[e * 68 + lane] = (pre > 0.f) ? pre : SLOPE * pre;
        }
    }
    __syncthreads();

    float acc[5][4];
    gemm_acc(h1s, Ws, b2, acc, t);      // GEMM1
    __syncthreads();

    {   // write h2 back into h1s; stage W3
        const int rg = t >> 4, og = t & 15;
        #pragma unroll
        for (int rr = 0; rr < 5; ++rr)
            #pragma unroll
            for (int oc = 0; oc < 4; ++oc) {
                float v = acc[rr][oc];
                v = (v > 0.f) ? v : SLOPE * v;
                h1s[(5 * rg + rr) * 68 + 4 * og + oc] = v;
            }
        for (int i = t; i < 4096; i += 256) Ws[i] = W3[i];
    }
    __syncthreads();

    gemm_acc(h1s, Ws, b3, acc, t);      // GEMM2
    {   // max over each thread's 5 rows (within one point: 20 % 5 == 0)
        const int rg = t >> 4, og = t & 15;
        #pragma unroll
        for (int oc = 0; oc < 4; ++oc) {
            float m = -1e30f;
            #pragma unroll
            for (int rr = 0; rr < 5; ++rr) {
                float v = acc[rr][oc];
                v = (v > 0.f) ? v : SLOPE * v;
                m = fmaxf(m, v);
            }
            mxs[rg * 64 + 4 * og + oc] = m;
        }
    }
    __syncthreads();

    const int p = t >> 6, col = t & 63;
    const float m = fmaxf(fmaxf(mxs[(4 * p + 0) * 64 + col], mxs[(4 * p + 1) * 64 + col]),
                          fmaxf(mxs[(4 * p + 2) * 64 + col], mxs[(4 * p + 3) * 64 + col]));
    out[(size_t)(p0 + p) * 64 + col] = m;
}

// ---------------------------------------------------------------------------
extern "C" void kernel_launch(void* const* d_in, const int* in_sizes, int n_in,
                              void* d_out, int out_size, void* d_ws, size_t ws_size,
                              hipStream_t stream) {
    const float* pos = (const float*)d_in[0];
    const float* w11 = (const float*)d_in[1];  const float* b11 = (const float*)d_in[2];
    const float* w12 = (const float*)d_in[3];  const float* b12 = (const float*)d_in[4];
    const float* w13 = (const float*)d_in[5];  const float* b13 = (const float*)d_in[6];
    const float* w21 = (const float*)d_in[7];  const float* b21 = (const float*)d_in[8];
    const float* w22 = (const float*)d_in[9];  const float* b22 = (const float*)d_in[10];
    const float* w23 = (const float*)d_in[11]; const float* b23 = (const float*)d_in[12];
    const float* w31 = (const float*)d_in[13]; const float* b31 = (const float*)d_in[14];
    const float* w32 = (const float*)d_in[15]; const float* b32 = (const float*)d_in[16];
    const float* w33 = (const float*)d_in[17]; const float* b33 = (const float*)d_in[18];

    const int BN = BATCH * NPTS;   // 32768
    // Simple workspace (no aliasing): [sqb][idx][x1][u][c][x2] = 36.3 MB
    float* ws = (float*)d_ws;
    float* sqb = ws;                                  // [BN]
    int*   idx = (int*)(sqb + BN);                    // [BN][20]
    float* x1  = (float*)(idx + (size_t)BN * KNN);    // [BN][64]
    float* ubuf = x1 + (size_t)BN * 64;               // [BN][64]
    float* cbuf = ubuf + (size_t)BN * 64;             // [BN][64]
    float* x2  = cbuf + (size_t)BN * 64;              // [BN][64]

    const dim3 knn_grid(NPTS / 64, BATCH);            // (64, 8) = 512 blocks

    // ---- EdgeConv 1 (D=3)
    sq_kernel<3><<<BN / 256, 256, 0, stream>>>(pos, sqb);
    knn3_kernel<3><<<knn_grid, BTHR, 0, stream>>>(pos, sqb, idx);
    uc_kernel<3><<<BN / 16, 256, 0, stream>>>(pos, w11, b11, ubuf, cbuf);
    edge_kernel<<<BN / 4, 256, 0, stream>>>(ubuf, cbuf, idx, w12, b12, w13, b13, x1);

    // ---- EdgeConv 2 (D=64)
    sq_kernel<64><<<BN / 256, 256, 0, stream>>>(x1, sqb);
    knn3_kernel<64><<<knn_grid, BTHR, 0, stream>>>(x1, sqb, idx);
    uc_kernel<64><<<BN / 16, 256, 0, stream>>>(x1, w21, b21, ubuf, cbuf);
    edge_kernel<<<BN / 4, 256, 0, stream>>>(ubuf, cbuf, idx, w22, b22, w23, b23, x2);

    // ---- EdgeConv 3 (D=64)
    sq_kernel<64><<<BN / 256, 256, 0, stream>>>(x2, sqb);
    knn3_kernel<64><<<knn_grid, BTHR, 0, stream>>>(x2, sqb, idx);
    uc_kernel<64><<<BN / 16, 256, 0, stream>>>(x2, w31, b31, ubuf, cbuf);
    edge_kernel<<<BN / 4, 256, 0, stream>>>(ubuf, cbuf, idx, w32, b32, w33, b33, (float*)d_out);
}